// Round 7
// baseline (420.700 us; speedup 1.0000x reference)
//
#include <hip/hip_runtime.h>
#include <hip/hip_bf16.h>
#include <math.h>

// Problem constants
#define B_    256
#define L_    200
#define H_    256
#define MAXT  256
#define SIXH  1536
#define FOURH 1024
#define NPOS  (B_ * L_)   // 51200

typedef __attribute__((ext_vector_type(8))) short short8;
typedef __attribute__((ext_vector_type(4))) float f32x4;

typedef __attribute__((address_space(3))) void lds_void;
typedef const __attribute__((address_space(1))) void gbl_void;

#define ASM_BAR() asm volatile("s_barrier" ::: "memory")
#define VMCNT4()  asm volatile("s_waitcnt vmcnt(4)" ::: "memory")
#define VMCNT0()  asm volatile("s_waitcnt vmcnt(0)" ::: "memory")

// ---------------------------------------------------------------------------
// Exclusive prefix-sum of lengths -> offsets[0..B_], offsets[B_] = total valid
// ---------------------------------------------------------------------------
__global__ void scan_offsets(const int* __restrict__ lengths,
                             int* __restrict__ offsets) {
  if (threadIdx.x == 0) {
    int acc = 0;
    for (int b = 0; b < B_; b++) { offsets[b] = acc; acc += lengths[b]; }
    offsets[B_] = acc;
  }
}

// ---------------------------------------------------------------------------
// Zero the pad rows of x: rows [total, roundup256(total))
// ---------------------------------------------------------------------------
__global__ void zero_pad_x(__hip_bfloat16* __restrict__ x,
                           const int* __restrict__ offsets) {
  int total = offsets[B_];
  int padded = (total + 255) & ~255;
  int row = total + blockIdx.x;
  if (row >= padded) return;
  int t = threadIdx.x;
#pragma unroll
  for (int j = 0; j < 6; j++)
    x[(size_t)row * SIXH + j * 256 + t] = __float2bfloat16(0.0f);
}

// ---------------------------------------------------------------------------
// Per compacted row: absolute output slot b*MAXT+p (or -1).
// ---------------------------------------------------------------------------
__global__ void tpos_kernel(const int* __restrict__ gids,
                            const int* __restrict__ lengths,
                            const int* __restrict__ offsets,
                            int* __restrict__ tpos) {
  int b = blockIdx.x, t = threadIdx.x;
  __shared__ int g[L_];
  int len = lengths[b];
  for (int l = t; l < len; l += 64) g[l] = gids[b * L_ + l];
  __syncthreads();
  if (t != 0) return;
  int base = offsets[b];
  int nsep = 0;
  for (int l = 0; l + 1 < len; l++)
    if (g[l] != g[l + 1]) nsep++;
  int total = len + nsep;
  int off = MAXT - total;
  int sb = 0;
  for (int l = 0; l < len; l++) {
    int ti = off + l + sb;
    tpos[base + l] = (ti >= 0) ? (b * MAXT + ti) : -1;
    if (l + 1 < len && g[l] != g[l + 1]) sb++;
  }
}

// ---------------------------------------------------------------------------
// Transpose + f32->bf16 convert: in [R][C] f32 -> out [C][R] bf16
// ---------------------------------------------------------------------------
__global__ void transpose_to_bf16(const float* __restrict__ in,
                                  __hip_bfloat16* __restrict__ out,
                                  int R, int C) {
  __shared__ float tile[32][33];
  int tc = blockIdx.x, tr = blockIdx.y;
  int tx = threadIdx.x & 31, ty = threadIdx.x >> 5;  // 32 x 8
#pragma unroll
  for (int i = 0; i < 4; i++) {
    int r = tr * 32 + ty + i * 8;
    int c = tc * 32 + tx;
    tile[ty + i * 8][tx] = in[(size_t)r * C + c];
  }
  __syncthreads();
#pragma unroll
  for (int i = 0; i < 4; i++) {
    int orow = tc * 32 + ty + i * 8;  // out row = original col
    int ocol = tr * 32 + tx;          // out col = original row
    out[(size_t)orow * R + ocol] = __float2bfloat16(tile[tx][ty + i * 8]);
  }
}

// ---------------------------------------------------------------------------
// Fused embedding gather + concat + LayerNorm -> x bf16 [row][1536]
// 384 threads = 6 waves; wave j handles table j; thread = float4 (4 channels).
// ---------------------------------------------------------------------------
__global__ void embed_ln_kernel(const int* __restrict__ tok0,
                                const int* __restrict__ tok1,
                                const int* __restrict__ tok2,
                                const int* __restrict__ tok3,
                                const int* __restrict__ tgap,
                                const int* __restrict__ gid,
                                const int* __restrict__ lengths,
                                const int* __restrict__ offsets,
                                const float* __restrict__ token_emb,
                                const float* __restrict__ tg_emb,
                                const float* __restrict__ g_emb,
                                const float* __restrict__ gamma,
                                const float* __restrict__ beta,
                                __hip_bfloat16* __restrict__ xout) {
  int l = blockIdx.x, b = blockIdx.y;
  if (l >= lengths[b]) return;  // compaction: skip invalid positions
  int pos = b * L_ + l;
  int row = offsets[b] + l;
  int t = threadIdx.x;
  int wv = t >> 6;          // table index 0..5
  int ln = t & 63;
  int c4 = ln * 4;          // channel within table

  const float* tab;
  int idx;
  if (wv == 0)      { tab = token_emb; idx = tok0[pos]; }
  else if (wv == 1) { tab = token_emb; idx = tok1[pos]; }
  else if (wv == 2) { tab = token_emb; idx = tok2[pos]; }
  else if (wv == 3) { tab = token_emb; idx = tok3[pos]; }
  else if (wv == 4) { tab = tg_emb;    idx = min(max(tgap[pos], 0), 64); }
  else              { tab = g_emb;     idx = gid[pos]; }

  float4 v = *(const float4*)&tab[(size_t)idx * H_ + c4];

  float s = v.x + v.y + v.z + v.w;
  float q = v.x * v.x + v.y * v.y + v.z * v.z + v.w * v.w;
#pragma unroll
  for (int o = 32; o; o >>= 1) { s += __shfl_down(s, o); q += __shfl_down(q, o); }
  __shared__ float ps[6], pq[6];
  if (ln == 0) { ps[wv] = s; pq[wv] = q; }
  __syncthreads();
  float ts = 0.f, tq = 0.f;
#pragma unroll
  for (int k = 0; k < 6; k++) { ts += ps[k]; tq += pq[k]; }
  float mu = ts * (1.0f / 1536.0f);
  float var = tq * (1.0f / 1536.0f) - mu * mu;
  float rstd = rsqrtf(var + 1e-5f);

  int cbase = wv * 256 + c4;
  float4 gm = *(const float4*)&gamma[cbase];
  float4 bt = *(const float4*)&beta[cbase];
  float y0 = (v.x - mu) * rstd * gm.x + bt.x;
  float y1 = (v.y - mu) * rstd * gm.y + bt.y;
  float y2 = (v.z - mu) * rstd * gm.z + bt.z;
  float y3 = (v.w - mu) * rstd * gm.w + bt.w;
  __hip_bfloat16 h0 = __float2bfloat16(y0), h1 = __float2bfloat16(y1);
  __hip_bfloat16 h2 = __float2bfloat16(y2), h3 = __float2bfloat16(y3);
  ushort4 pk;
  pk.x = *(unsigned short*)&h0; pk.y = *(unsigned short*)&h1;
  pk.z = *(unsigned short*)&h2; pk.w = *(unsigned short*)&h3;
  *(ushort4*)&xout[(size_t)row * SIXH + cbase] = pk;
}

// ---------------------------------------------------------------------------
// GEMM1 (persistent, XCD-sibling-grouped): 256x256 tile, BK=64, 8 waves,
// 8-phase schedule, counted vmcnt(4), XOR-swizzled LDS (0 conflicts, R4).
// Mapping: bid = xcd + 8*(nt + 4*mtb). The 4 nt-siblings of each mt share
// bid%8 (same XCD under round-robin bid->XCD) AND are adjacent in bid
// (differ by 8) -> A K-tiles fetched once into the XCD's L2 and hit 3x;
// staging becomes L2-served (the R6 post-mortem's starvation fix).
// Loop: mt = xcd + 8*mtb + 64*iter (bijective over mt).
// ---------------------------------------------------------------------------
__global__ __launch_bounds__(512, 2)
void gemm1_8ph(const __hip_bfloat16* __restrict__ A,
               const __hip_bfloat16* __restrict__ Bt,
               const float* __restrict__ bias,
               __hip_bfloat16* __restrict__ out,
               const int* __restrict__ total_ptr) {
  constexpr int K = SIXH;     // 1536
  constexpr int NT = K / 64;  // 24 K-tiles
  constexpr int N = FOURH;    // 1024

  extern __shared__ __align__(16) char lds[];

  int total = total_ptr[0];
  int padded = (total + 255) & ~255;
  int num_mt = padded >> 8;

  int bid = blockIdx.x;        // 0..255
  int xcd = bid & 7;
  int slot = bid >> 3;         // 0..31
  int nt = slot & 3;           // 0..3
  int mtb = slot >> 2;         // 0..7
  int n0 = nt * 256;

  int tid = threadIdx.x;
  int lane = tid & 63;
  int w = tid >> 6;
  int wave_m = w >> 2;
  int wave_n = w & 3;

  int r15 = lane & 15, g = lane >> 4;
  int slot_r = (((r15 & 1) << 2) | g) ^ (r15 >> 1);
  int lane_off = (r15 >> 1) * 128 + slot_r * 16;

  int s0 = (tid & 7) ^ ((tid >> 3) & 7);
  int scol = (s0 & 3) * 8;
  int row0 = ((tid >> 3) << 1) + (s0 >> 2);
  int ldst0 = w * 1024;

  // bias hoist: 4 cols per thread, fixed for the whole block
  float bv4[4];
#pragma unroll
  for (int ni = 0; ni < 4; ni++)
    bv4[ni] = bias[n0 + wave_n * 64 + ni * 16 + r15];

#define REGA(d, h) (lds + (d) * 65536 + (h) * 16384)
#define REGB(d, h) (lds + (d) * 65536 + 32768 + (h) * 16384)

#define STAGE(P, t0, kt, h, rb)                                                \
  do {                                                                         \
    __builtin_amdgcn_global_load_lds(                                          \
        (gbl_void*)((P) + (size_t)((t0) + row0) * K + (kt) * 64 + (h) * 32 +   \
                    scol),                                                     \
        (lds_void*)((rb) + ldst0), 16, 0, 0);                                  \
    __builtin_amdgcn_global_load_lds(                                          \
        (gbl_void*)((P) + (size_t)((t0) + row0 + 128) * K + (kt) * 64 +        \
                    (h) * 32 + scol),                                          \
        (lds_void*)((rb) + 8192 + ldst0), 16, 0, 0);                           \
  } while (0)

  for (int mt = xcd + 8 * mtb; mt < num_mt; mt += 64) {
    int m0 = mt * 256;

    f32x4 acc[8][4] = {};

    // prologue: kt0 fully + kt1 khalf0 (12 loads; vmcnt(4) => kt0 resident)
    STAGE(A, m0, 0, 0, REGA(0, 0));
    STAGE(Bt, n0, 0, 0, REGB(0, 0));
    STAGE(A, m0, 0, 1, REGA(0, 1));
    STAGE(Bt, n0, 0, 1, REGB(0, 1));
    STAGE(A, m0, 1, 0, REGA(1, 0));
    STAGE(Bt, n0, 1, 0, REGB(1, 0));
    VMCNT4();
    ASM_BAR();

    for (int kt = 0; kt < NT; ++kt) {
      int d = kt & 1;
      int kc1 = (kt + 1 < NT) ? kt + 1 : NT - 1;
      int kc2 = (kt + 2 < NT) ? kt + 2 : NT - 1;
      char* A0 = REGA(d, 0); char* A1 = REGA(d, 1);
      char* B0 = REGB(d, 0); char* B1 = REGB(d, 1);
      char* An1 = REGA(d ^ 1, 1);
      char* Bn1 = REGB(d ^ 1, 1);

      short8 a[4], b[4];

      // ---- phase 0: kh0, mi 0-3 ; stage A(kt+1, kh1)
#pragma unroll
      for (int ni = 0; ni < 4; ni++)
        b[ni] = *(const short8*)(B0 + (wave_n * 64 + ni * 16) * 64 + lane_off);
#pragma unroll
      for (int j = 0; j < 4; j++)
        a[j] = *(const short8*)(A0 + (wave_m * 128 + j * 16) * 64 + lane_off);
      STAGE(A, m0, kc1, 1, An1);
      ASM_BAR();
      __builtin_amdgcn_s_setprio(1);
#pragma unroll
      for (int j = 0; j < 4; j++)
#pragma unroll
        for (int ni = 0; ni < 4; ni++)
          acc[j][ni] = __builtin_amdgcn_mfma_f32_16x16x32_bf16(a[j], b[ni],
                                                               acc[j][ni], 0, 0, 0);
      __builtin_amdgcn_s_setprio(0);
      ASM_BAR();

      // ---- phase 1: kh0, mi 4-7 ; stage B(kt+1, kh1)
#pragma unroll
      for (int j = 0; j < 4; j++)
        a[j] = *(const short8*)(A0 + (wave_m * 128 + (4 + j) * 16) * 64 + lane_off);
      STAGE(Bt, n0, kc1, 1, Bn1);
      ASM_BAR();
      __builtin_amdgcn_s_setprio(1);
#pragma unroll
      for (int j = 0; j < 4; j++)
#pragma unroll
        for (int ni = 0; ni < 4; ni++)
          acc[4 + j][ni] = __builtin_amdgcn_mfma_f32_16x16x32_bf16(
              a[j], b[ni], acc[4 + j][ni], 0, 0, 0);
      __builtin_amdgcn_s_setprio(0);
      ASM_BAR();

      // ---- phase 2: kh1, mi 0-3 ; stage A(kt+2, kh0) -> overwrites A0 (dead)
#pragma unroll
      for (int ni = 0; ni < 4; ni++)
        b[ni] = *(const short8*)(B1 + (wave_n * 64 + ni * 16) * 64 + lane_off);
#pragma unroll
      for (int j = 0; j < 4; j++)
        a[j] = *(const short8*)(A1 + (wave_m * 128 + j * 16) * 64 + lane_off);
      STAGE(A, m0, kc2, 0, A0);
      ASM_BAR();
      __builtin_amdgcn_s_setprio(1);
#pragma unroll
      for (int j = 0; j < 4; j++)
#pragma unroll
        for (int ni = 0; ni < 4; ni++)
          acc[j][ni] = __builtin_amdgcn_mfma_f32_16x16x32_bf16(a[j], b[ni],
                                                               acc[j][ni], 0, 0, 0);
      __builtin_amdgcn_s_setprio(0);
      ASM_BAR();

      // ---- phase 3: kh1, mi 4-7 ; stage B(kt+2, kh0) ; counted vmcnt(4)
#pragma unroll
      for (int j = 0; j < 4; j++)
        a[j] = *(const short8*)(A1 + (wave_m * 128 + (4 + j) * 16) * 64 + lane_off);
      STAGE(Bt, n0, kc2, 0, B0);
      ASM_BAR();
      __builtin_amdgcn_s_setprio(1);
#pragma unroll
      for (int j = 0; j < 4; j++)
#pragma unroll
        for (int ni = 0; ni < 4; ni++)
          acc[4 + j][ni] = __builtin_amdgcn_mfma_f32_16x16x32_bf16(
              a[j], b[ni], acc[4 + j][ni], 0, 0, 0);
      __builtin_amdgcn_s_setprio(0);
      VMCNT4();
      ASM_BAR();
    }
    // drain stale clamped stage-loads before LDS regions are re-staged.
    VMCNT0();

    // epilogue: D mapping col = lane&15, row = 4*(lane>>4)+reg
    int r0 = g * 4;
#pragma unroll
    for (int mi = 0; mi < 8; mi++)
#pragma unroll
      for (int ni = 0; ni < 4; ni++) {
        int col = n0 + wave_n * 64 + ni * 16 + r15;
        float bv = bv4[ni];
#pragma unroll
        for (int r = 0; r < 4; r++) {
          int row = m0 + wave_m * 128 + mi * 16 + r0 + r;
          float v = acc[mi][ni][r] + bv;
          v = v / (1.0f + __expf(-v));  // silu
          out[(size_t)row * N + col] = __float2bfloat16(v);
        }
      }
  }
#undef STAGE
#undef REGA
#undef REGB
}

// ---------------------------------------------------------------------------
// GEMM2 with fused scatter epilogue. Reshaped: BM=128, BN=256 (FULL N) so
// the A(h) panel is staged exactly once (was 2x). 256 thr = 4 waves (2m x 2n,
// wave out 64x128). LDS 48KB. Writes directly to d_out at tpos[row]+pos_emb.
// ---------------------------------------------------------------------------
__global__ void gemm2_scatter(const __hip_bfloat16* __restrict__ A,
                              const __hip_bfloat16* __restrict__ Bt,
                              const float* __restrict__ bias,
                              const int* __restrict__ tpos,
                              const float* __restrict__ pos_emb,
                              float* __restrict__ out,
                              const int* __restrict__ total_ptr) {
  constexpr int K = FOURH;  // 1024
  int m0 = blockIdx.x * 128;
  int total = total_ptr[0];
  int padded = (total + 127) & ~127;
  if (m0 >= padded) return;

  __shared__ __hip_bfloat16 As[128 * 64];  // 16KB
  __shared__ __hip_bfloat16 Bs[256 * 64];  // 32KB
  int tid = threadIdx.x;
  int lane = tid & 63, wid = tid >> 6;
  int wm = (wid >> 1) * 64;    // 0 or 64
  int wn = (wid & 1) * 128;    // 0 or 128

  int srow = (lane >> 3);
  int scol = (lane & 7) * 8;
  int r15 = lane & 15, g = lane >> 4;

  f32x4 acc[4][8] = {};

  for (int k0 = 0; k0 < K; k0 += 64) {
    // A: 16 chunks of 1KB (8 rows each); wave w does 4
#pragma unroll
    for (int i = 0; i < 4; i++) {
      int c = wid * 4 + i;
      int row = c * 8 + srow;
      __builtin_amdgcn_global_load_lds(
          (gbl_void*)&A[(size_t)(m0 + row) * K + k0 + scol],
          (lds_void*)(As + c * 512), 16, 0, 0);
    }
    // B: 32 chunks; wave w does 8
#pragma unroll
    for (int i = 0; i < 8; i++) {
      int c = wid * 8 + i;
      int row = c * 8 + srow;
      __builtin_amdgcn_global_load_lds(
          (gbl_void*)&Bt[(size_t)row * K + k0 + scol],
          (lds_void*)(Bs + c * 512), 16, 0, 0);
    }
    __syncthreads();
#pragma unroll
    for (int kk = 0; kk < 64; kk += 32) {
      short8 a[4], bb[8];
#pragma unroll
      for (int m = 0; m < 4; m++)
        a[m] = *(const short8*)&As[(wm + m * 16 + r15) * 64 + kk + 8 * g];
#pragma unroll
      for (int n = 0; n < 8; n++)
        bb[n] = *(const short8*)&Bs[(wn + n * 16 + r15) * 64 + kk + 8 * g];
#pragma unroll
      for (int m = 0; m < 4; m++)
#pragma unroll
        for (int n = 0; n < 8; n++)
          acc[m][n] = __builtin_amdgcn_mfma_f32_16x16x32_bf16(a[m], bb[n],
                                                              acc[m][n], 0, 0, 0);
    }
    __syncthreads();
  }

  int r0 = g * 4;
#pragma unroll
  for (int m = 0; m < 4; m++) {
#pragma unroll
    for (int r = 0; r < 4; r++) {
      int row = m0 + wm + m * 16 + r0 + r;
      if (row >= total) continue;
      int pa = tpos[row];
      if (pa < 0) continue;
      int p = pa & (MAXT - 1);
#pragma unroll
      for (int n = 0; n < 8; n++) {
        int col = wn + n * 16 + r15;
        float v = acc[m][n][r] + bias[col] + pos_emb[p * H_ + col];
        out[(size_t)pa * H_ + col] = v;
      }
    }
  }
}

// ---------------------------------------------------------------------------
// merge2: sep rows (sep_token + pos_emb), zero-fill empty positions, mm.
// Token positions already written by gemm2_scatter.
// ---------------------------------------------------------------------------
__global__ void merge2_kernel(const int* __restrict__ gids,
                              const int* __restrict__ lengths,
                              const float* __restrict__ sep_token,
                              const float* __restrict__ pos_emb,
                              float* __restrict__ out) {
  int b = blockIdx.x, t = threadIdx.x;
  __shared__ signed char src[MAXT];  // 0 empty, 1 sep, 2 token
  __shared__ int g[L_];
  __shared__ int sh_total;
  int len = lengths[b];
  src[t] = 0;
  for (int l = t; l < len; l += 256) g[l] = gids[b * L_ + l];
  __syncthreads();
  if (t == 0) {
    int nsep = 0;
    for (int l = 0; l + 1 < len; l++)
      if (g[l] != g[l + 1]) nsep++;
    int total = len + nsep;
    sh_total = total;
    int off = MAXT - total;
    int sb = 0;
    for (int l = 0; l < len; l++) {
      int ti = off + l + sb;
      if (ti >= 0) src[ti] = 2;
      if (l + 1 < len && g[l] != g[l + 1]) {
        if (ti + 1 >= 0) src[ti + 1] = 1;
        sb++;
      }
    }
  }
  __syncthreads();
  int total = sh_total;
  int mlen = min(total, MAXT);

  int q = t >> 6, lane = t & 63, c4 = lane * 4;
  float4 sep4 = *(const float4*)&sep_token[c4];
  float* orow = out + (size_t)b * MAXT * H_;
  for (int p0 = 0; p0 < MAXT; p0 += 4) {
    int p = p0 + q;
    int s = src[p];
    if (s == 2) continue;  // token: written by gemm2_scatter
    float4 v;
    if (s == 1) {
      float4 pe = *(const float4*)&pos_emb[p * H_ + c4];
      v.x = sep4.x + pe.x; v.y = sep4.y + pe.y;
      v.z = sep4.z + pe.z; v.w = sep4.w + pe.w;
    } else {
      v.x = 0.f; v.y = 0.f; v.z = 0.f; v.w = 0.f;
    }
    *(float4*)&orow[(size_t)p * H_ + c4] = v;
  }
  float* mm = out + (size_t)B_ * MAXT * H_;
  mm[b * MAXT + t] = (t >= MAXT - mlen) ? 1.0f : 0.0f;
}

// ---------------------------------------------------------------------------
// launch
// ---------------------------------------------------------------------------
extern "C" void kernel_launch(void* const* d_in, const int* in_sizes, int n_in,
                              void* d_out, int out_size, void* d_ws,
                              size_t ws_size, hipStream_t stream) {
  const int* tok0 = (const int*)d_in[0];
  const int* tok1 = (const int*)d_in[1];
  const int* tok2 = (const int*)d_in[2];
  const int* tok3 = (const int*)d_in[3];
  const int* tgap = (const int*)d_in[4];
  const int* gid  = (const int*)d_in[5];
  const int* lengths = (const int*)d_in[6];
  const float* token_emb = (const float*)d_in[7];
  const float* gamma = (const float*)d_in[8];
  const float* beta  = (const float*)d_in[9];
  const float* w1 = (const float*)d_in[10];
  const float* b1 = (const float*)d_in[11];
  const float* w2 = (const float*)d_in[12];
  const float* b2 = (const float*)d_in[13];
  const float* tg_emb = (const float*)d_in[14];
  const float* g_emb  = (const float*)d_in[15];
  const float* pos_emb = (const float*)d_in[16];
  const float* sep_tok = (const float*)d_in[17];

  // workspace layout (bytes):
  //   x     bf16 [<=51200][1536] @ 0          (157,286,400)
  //   tpos  int  [<=51200]       @ 0          (aliases x; written after GEMM1)
  //   h     bf16 [<=51200][1024] @ 157286400  (104,857,600)
  //   w1t   bf16 [1024][1536]    @ 262144000  (  3,145,728)
  //   w2t   bf16 [256][1024]     @ 265289728  (    524,288)
  //   offsets int[257]           @ 265814016  (      1,028)
  const size_t NEEDED = 265815044;
  if (ws_size < NEEDED) return;

  char* ws = (char*)d_ws;
  __hip_bfloat16* x = (__hip_bfloat16*)ws;
  int* tpos = (int*)ws;  // aliases x (x dead after GEMM1)
  __hip_bfloat16* h = (__hip_bfloat16*)(ws + 157286400);
  __hip_bfloat16* w1t = (__hip_bfloat16*)(ws + 262144000);
  __hip_bfloat16* w2t = (__hip_bfloat16*)(ws + 265289728);
  int* offsets = (int*)(ws + 265814016);

  scan_offsets<<<1, 64, 0, stream>>>(lengths, offsets);
  zero_pad_x<<<256, 256, 0, stream>>>(x, offsets);

  transpose_to_bf16<<<dim3(1024 / 32, 1536 / 32), 256, 0, stream>>>(w1, w1t,
                                                                    1536, 1024);
  transpose_to_bf16<<<dim3(256 / 32, 1024 / 32), 256, 0, stream>>>(w2, w2t,
                                                                   1024, 256);

  embed_ln_kernel<<<dim3(L_, B_), 384, 0, stream>>>(
      tok0, tok1, tok2, tok3, tgap, gid, lengths, offsets, token_emb, tg_emb,
      g_emb, gamma, beta, x);

  hipFuncSetAttribute((const void*)gemm1_8ph,
                      hipFuncAttributeMaxDynamicSharedMemorySize, 131072);
  gemm1_8ph<<<256, 512, 131072, stream>>>(x, w1t, b1, h, offsets + B_);

  // x now dead -> tpos may overwrite its region
  tpos_kernel<<<B_, 64, 0, stream>>>(gid, lengths, offsets, tpos);

  gemm2_scatter<<<NPOS / 128, 256, 0, stream>>>(h, w2t, b2, tpos, pos_emb,
                                                (float*)d_out, offsets + B_);

  merge2_kernel<<<B_, 256, 0, stream>>>(gid, lengths, sep_tok, pos_emb,
                                        (float*)d_out);
}

// Round 8
// 257.255 us; speedup vs baseline: 1.6353x; 1.6353x over previous
//
#include <hip/hip_runtime.h>
#include <hip/hip_bf16.h>
#include <math.h>

// Problem constants
#define B_    256
#define L_    200
#define H_    256
#define MAXT  256
#define SIXH  1536
#define FOURH 1024
#define NPOS  (B_ * L_)   // 51200

typedef __attribute__((ext_vector_type(8))) short short8;
typedef __attribute__((ext_vector_type(4))) float f32x4;

typedef __attribute__((address_space(3))) void lds_void;
typedef const __attribute__((address_space(1))) void gbl_void;

#define ASM_BAR() asm volatile("s_barrier" ::: "memory")
#define VMCNT4()  asm volatile("s_waitcnt vmcnt(4)" ::: "memory")
#define VMCNT0()  asm volatile("s_waitcnt vmcnt(0)" ::: "memory")

// ---------------------------------------------------------------------------
// Exclusive prefix-sum of lengths -> offsets[0..B_], offsets[B_] = total valid
// ---------------------------------------------------------------------------
__global__ void scan_offsets(const int* __restrict__ lengths,
                             int* __restrict__ offsets) {
  if (threadIdx.x == 0) {
    int acc = 0;
    for (int b = 0; b < B_; b++) { offsets[b] = acc; acc += lengths[b]; }
    offsets[B_] = acc;
  }
}

// ---------------------------------------------------------------------------
// Zero the pad rows of x: rows [total, roundup256(total))
// ---------------------------------------------------------------------------
__global__ void zero_pad_x(__hip_bfloat16* __restrict__ x,
                           const int* __restrict__ offsets) {
  int total = offsets[B_];
  int padded = (total + 255) & ~255;
  int row = total + blockIdx.x;
  if (row >= padded) return;
  int t = threadIdx.x;
#pragma unroll
  for (int j = 0; j < 6; j++)
    x[(size_t)row * SIXH + j * 256 + t] = __float2bfloat16(0.0f);
}

// ---------------------------------------------------------------------------
// Per compacted row: absolute output slot b*MAXT+p (or -1).
// ---------------------------------------------------------------------------
__global__ void tpos_kernel(const int* __restrict__ gids,
                            const int* __restrict__ lengths,
                            const int* __restrict__ offsets,
                            int* __restrict__ tpos) {
  int b = blockIdx.x, t = threadIdx.x;
  __shared__ int g[L_];
  int len = lengths[b];
  for (int l = t; l < len; l += 64) g[l] = gids[b * L_ + l];
  __syncthreads();
  if (t != 0) return;
  int base = offsets[b];
  int nsep = 0;
  for (int l = 0; l + 1 < len; l++)
    if (g[l] != g[l + 1]) nsep++;
  int total = len + nsep;
  int off = MAXT - total;
  int sb = 0;
  for (int l = 0; l < len; l++) {
    int ti = off + l + sb;
    tpos[base + l] = (ti >= 0) ? (b * MAXT + ti) : -1;
    if (l + 1 < len && g[l] != g[l + 1]) sb++;
  }
}

// ---------------------------------------------------------------------------
// Transpose + f32->bf16 convert: in [R][C] f32 -> out [C][R] bf16
// ---------------------------------------------------------------------------
__global__ void transpose_to_bf16(const float* __restrict__ in,
                                  __hip_bfloat16* __restrict__ out,
                                  int R, int C) {
  __shared__ float tile[32][33];
  int tc = blockIdx.x, tr = blockIdx.y;
  int tx = threadIdx.x & 31, ty = threadIdx.x >> 5;  // 32 x 8
#pragma unroll
  for (int i = 0; i < 4; i++) {
    int r = tr * 32 + ty + i * 8;
    int c = tc * 32 + tx;
    tile[ty + i * 8][tx] = in[(size_t)r * C + c];
  }
  __syncthreads();
#pragma unroll
  for (int i = 0; i < 4; i++) {
    int orow = tc * 32 + ty + i * 8;  // out row = original col
    int ocol = tr * 32 + tx;          // out col = original row
    out[(size_t)orow * R + ocol] = __float2bfloat16(tile[tx][ty + i * 8]);
  }
}

// ---------------------------------------------------------------------------
// Fused embedding gather + concat + LayerNorm -> x bf16 [row][1536]
// 384 threads = 6 waves; wave j handles table j; thread = float4 (4 channels).
// ---------------------------------------------------------------------------
__global__ void embed_ln_kernel(const int* __restrict__ tok0,
                                const int* __restrict__ tok1,
                                const int* __restrict__ tok2,
                                const int* __restrict__ tok3,
                                const int* __restrict__ tgap,
                                const int* __restrict__ gid,
                                const int* __restrict__ lengths,
                                const int* __restrict__ offsets,
                                const float* __restrict__ token_emb,
                                const float* __restrict__ tg_emb,
                                const float* __restrict__ g_emb,
                                const float* __restrict__ gamma,
                                const float* __restrict__ beta,
                                __hip_bfloat16* __restrict__ xout) {
  int l = blockIdx.x, b = blockIdx.y;
  if (l >= lengths[b]) return;  // compaction: skip invalid positions
  int pos = b * L_ + l;
  int row = offsets[b] + l;
  int t = threadIdx.x;
  int wv = t >> 6;          // table index 0..5
  int ln = t & 63;
  int c4 = ln * 4;          // channel within table

  const float* tab;
  int idx;
  if (wv == 0)      { tab = token_emb; idx = tok0[pos]; }
  else if (wv == 1) { tab = token_emb; idx = tok1[pos]; }
  else if (wv == 2) { tab = token_emb; idx = tok2[pos]; }
  else if (wv == 3) { tab = token_emb; idx = tok3[pos]; }
  else if (wv == 4) { tab = tg_emb;    idx = min(max(tgap[pos], 0), 64); }
  else              { tab = g_emb;     idx = gid[pos]; }

  float4 v = *(const float4*)&tab[(size_t)idx * H_ + c4];

  float s = v.x + v.y + v.z + v.w;
  float q = v.x * v.x + v.y * v.y + v.z * v.z + v.w * v.w;
#pragma unroll
  for (int o = 32; o; o >>= 1) { s += __shfl_down(s, o); q += __shfl_down(q, o); }
  __shared__ float ps[6], pq[6];
  if (ln == 0) { ps[wv] = s; pq[wv] = q; }
  __syncthreads();
  float ts = 0.f, tq = 0.f;
#pragma unroll
  for (int k = 0; k < 6; k++) { ts += ps[k]; tq += pq[k]; }
  float mu = ts * (1.0f / 1536.0f);
  float var = tq * (1.0f / 1536.0f) - mu * mu;
  float rstd = rsqrtf(var + 1e-5f);

  int cbase = wv * 256 + c4;
  float4 gm = *(const float4*)&gamma[cbase];
  float4 bt = *(const float4*)&beta[cbase];
  float y0 = (v.x - mu) * rstd * gm.x + bt.x;
  float y1 = (v.y - mu) * rstd * gm.y + bt.y;
  float y2 = (v.z - mu) * rstd * gm.z + bt.z;
  float y3 = (v.w - mu) * rstd * gm.w + bt.w;
  __hip_bfloat16 h0 = __float2bfloat16(y0), h1 = __float2bfloat16(y1);
  __hip_bfloat16 h2 = __float2bfloat16(y2), h3 = __float2bfloat16(y3);
  ushort4 pk;
  pk.x = *(unsigned short*)&h0; pk.y = *(unsigned short*)&h1;
  pk.z = *(unsigned short*)&h2; pk.w = *(unsigned short*)&h3;
  *(ushort4*)&xout[(size_t)row * SIXH + cbase] = pk;
}

// ---------------------------------------------------------------------------
// GEMM1 (persistent, XCD-sibling-grouped): 256x256 tile, BK=64, 8 waves,
// 8-phase schedule, counted vmcnt(4), XOR-swizzled LDS (0 conflicts, R4).
// bid = xcd + 8*(nt + 4*mtb); loop mt = xcd + 8*mtb + 64*iter.
// ---------------------------------------------------------------------------
__global__ __launch_bounds__(512, 2)
void gemm1_8ph(const __hip_bfloat16* __restrict__ A,
               const __hip_bfloat16* __restrict__ Bt,
               const float* __restrict__ bias,
               __hip_bfloat16* __restrict__ out,
               const int* __restrict__ total_ptr) {
  constexpr int K = SIXH;     // 1536
  constexpr int NT = K / 64;  // 24 K-tiles
  constexpr int N = FOURH;    // 1024

  extern __shared__ __align__(16) char lds[];

  int total = total_ptr[0];
  int padded = (total + 255) & ~255;
  int num_mt = padded >> 8;

  int bid = blockIdx.x;        // 0..255
  int xcd = bid & 7;
  int slot = bid >> 3;         // 0..31
  int nt = slot & 3;           // 0..3
  int mtb = slot >> 2;         // 0..7
  int n0 = nt * 256;

  int tid = threadIdx.x;
  int lane = tid & 63;
  int w = tid >> 6;
  int wave_m = w >> 2;
  int wave_n = w & 3;

  int r15 = lane & 15, g = lane >> 4;
  int slot_r = (((r15 & 1) << 2) | g) ^ (r15 >> 1);
  int lane_off = (r15 >> 1) * 128 + slot_r * 16;

  int s0 = (tid & 7) ^ ((tid >> 3) & 7);
  int scol = (s0 & 3) * 8;
  int row0 = ((tid >> 3) << 1) + (s0 >> 2);
  int ldst0 = w * 1024;

  // bias hoist: 4 cols per thread, fixed for the whole block
  float bv4[4];
#pragma unroll
  for (int ni = 0; ni < 4; ni++)
    bv4[ni] = bias[n0 + wave_n * 64 + ni * 16 + r15];

#define REGA(d, h) (lds + (d) * 65536 + (h) * 16384)
#define REGB(d, h) (lds + (d) * 65536 + 32768 + (h) * 16384)

#define STAGE(P, t0, kt, h, rb)                                                \
  do {                                                                         \
    __builtin_amdgcn_global_load_lds(                                          \
        (gbl_void*)((P) + (size_t)((t0) + row0) * K + (kt) * 64 + (h) * 32 +   \
                    scol),                                                     \
        (lds_void*)((rb) + ldst0), 16, 0, 0);                                  \
    __builtin_amdgcn_global_load_lds(                                          \
        (gbl_void*)((P) + (size_t)((t0) + row0 + 128) * K + (kt) * 64 +        \
                    (h) * 32 + scol),                                          \
        (lds_void*)((rb) + 8192 + ldst0), 16, 0, 0);                           \
  } while (0)

  for (int mt = xcd + 8 * mtb; mt < num_mt; mt += 64) {
    int m0 = mt * 256;

    f32x4 acc[8][4] = {};

    // prologue: kt0 fully + kt1 khalf0 (12 loads; vmcnt(4) => kt0 resident)
    STAGE(A, m0, 0, 0, REGA(0, 0));
    STAGE(Bt, n0, 0, 0, REGB(0, 0));
    STAGE(A, m0, 0, 1, REGA(0, 1));
    STAGE(Bt, n0, 0, 1, REGB(0, 1));
    STAGE(A, m0, 1, 0, REGA(1, 0));
    STAGE(Bt, n0, 1, 0, REGB(1, 0));
    VMCNT4();
    ASM_BAR();

    for (int kt = 0; kt < NT; ++kt) {
      int d = kt & 1;
      int kc1 = (kt + 1 < NT) ? kt + 1 : NT - 1;
      int kc2 = (kt + 2 < NT) ? kt + 2 : NT - 1;
      char* A0 = REGA(d, 0); char* A1 = REGA(d, 1);
      char* B0 = REGB(d, 0); char* B1 = REGB(d, 1);
      char* An1 = REGA(d ^ 1, 1);
      char* Bn1 = REGB(d ^ 1, 1);

      short8 a[4], b[4];

      // ---- phase 0: kh0, mi 0-3 ; stage A(kt+1, kh1)
#pragma unroll
      for (int ni = 0; ni < 4; ni++)
        b[ni] = *(const short8*)(B0 + (wave_n * 64 + ni * 16) * 64 + lane_off);
#pragma unroll
      for (int j = 0; j < 4; j++)
        a[j] = *(const short8*)(A0 + (wave_m * 128 + j * 16) * 64 + lane_off);
      STAGE(A, m0, kc1, 1, An1);
      ASM_BAR();
      __builtin_amdgcn_s_setprio(1);
#pragma unroll
      for (int j = 0; j < 4; j++)
#pragma unroll
        for (int ni = 0; ni < 4; ni++)
          acc[j][ni] = __builtin_amdgcn_mfma_f32_16x16x32_bf16(a[j], b[ni],
                                                               acc[j][ni], 0, 0, 0);
      __builtin_amdgcn_s_setprio(0);
      ASM_BAR();

      // ---- phase 1: kh0, mi 4-7 ; stage B(kt+1, kh1)
#pragma unroll
      for (int j = 0; j < 4; j++)
        a[j] = *(const short8*)(A0 + (wave_m * 128 + (4 + j) * 16) * 64 + lane_off);
      STAGE(Bt, n0, kc1, 1, Bn1);
      ASM_BAR();
      __builtin_amdgcn_s_setprio(1);
#pragma unroll
      for (int j = 0; j < 4; j++)
#pragma unroll
        for (int ni = 0; ni < 4; ni++)
          acc[4 + j][ni] = __builtin_amdgcn_mfma_f32_16x16x32_bf16(
              a[j], b[ni], acc[4 + j][ni], 0, 0, 0);
      __builtin_amdgcn_s_setprio(0);
      ASM_BAR();

      // ---- phase 2: kh1, mi 0-3 ; stage A(kt+2, kh0) -> overwrites A0 (dead)
#pragma unroll
      for (int ni = 0; ni < 4; ni++)
        b[ni] = *(const short8*)(B1 + (wave_n * 64 + ni * 16) * 64 + lane_off);
#pragma unroll
      for (int j = 0; j < 4; j++)
        a[j] = *(const short8*)(A1 + (wave_m * 128 + j * 16) * 64 + lane_off);
      STAGE(A, m0, kc2, 0, A0);
      ASM_BAR();
      __builtin_amdgcn_s_setprio(1);
#pragma unroll
      for (int j = 0; j < 4; j++)
#pragma unroll
        for (int ni = 0; ni < 4; ni++)
          acc[j][ni] = __builtin_amdgcn_mfma_f32_16x16x32_bf16(a[j], b[ni],
                                                               acc[j][ni], 0, 0, 0);
      __builtin_amdgcn_s_setprio(0);
      ASM_BAR();

      // ---- phase 3: kh1, mi 4-7 ; stage B(kt+2, kh0) ; counted vmcnt(4)
#pragma unroll
      for (int j = 0; j < 4; j++)
        a[j] = *(const short8*)(A1 + (wave_m * 128 + (4 + j) * 16) * 64 + lane_off);
      STAGE(Bt, n0, kc2, 0, B0);
      ASM_BAR();
      __builtin_amdgcn_s_setprio(1);
#pragma unroll
      for (int j = 0; j < 4; j++)
#pragma unroll
        for (int ni = 0; ni < 4; ni++)
          acc[4 + j][ni] = __builtin_amdgcn_mfma_f32_16x16x32_bf16(
              a[j], b[ni], acc[4 + j][ni], 0, 0, 0);
      __builtin_amdgcn_s_setprio(0);
      VMCNT4();
      ASM_BAR();
    }
    // drain stale clamped stage-loads before LDS regions are re-staged.
    VMCNT0();

    // epilogue: D mapping col = lane&15, row = 4*(lane>>4)+reg
    int r0 = g * 4;
#pragma unroll
    for (int mi = 0; mi < 8; mi++)
#pragma unroll
      for (int ni = 0; ni < 4; ni++) {
        int col = n0 + wave_n * 64 + ni * 16 + r15;
        float bv = bv4[ni];
#pragma unroll
        for (int r = 0; r < 4; r++) {
          int row = m0 + wave_m * 128 + mi * 16 + r0 + r;
          float v = acc[mi][ni][r] + bv;
          v = v / (1.0f + __expf(-v));  // silu
          out[(size_t)row * N + col] = __float2bfloat16(v);
        }
      }
  }
#undef STAGE
#undef REGA
#undef REGB
}

// ---------------------------------------------------------------------------
// GEMM2 with fused scatter epilogue (REVERTED to proven 128x128 R5/R6 form:
// acc[4][4] = 64 acc VGPRs, no spill; R7's 128x256 reshape spilled acc to
// scratch -> VGPR_Count 64, 274MB scratch writes, 212us). C = h*w2t^T + b2,
// written to d_out at tpos[row] with pos_emb added.
// ---------------------------------------------------------------------------
__global__ void gemm2_scatter(const __hip_bfloat16* __restrict__ A,
                              const __hip_bfloat16* __restrict__ Bt,
                              const float* __restrict__ bias,
                              const int* __restrict__ tpos,
                              const float* __restrict__ pos_emb,
                              float* __restrict__ out,
                              const int* __restrict__ total_ptr,
                              int N, int K) {
  int m0 = blockIdx.y * 128;
  int total = total_ptr[0];
  int padded = (total + 127) & ~127;
  if (m0 >= padded) return;

  __shared__ __hip_bfloat16 As[128 * 64];
  __shared__ __hip_bfloat16 Bs[128 * 64];
  int n0 = blockIdx.x * 128;
  int tid = threadIdx.x;
  int lane = tid & 63, wid = tid >> 6;
  int wm = (wid >> 1) * 64, wn = (wid & 1) * 64;

  int srow = (lane >> 3);
  int scol = (lane & 7) * 8;

  f32x4 acc[4][4] = {};

  for (int k0 = 0; k0 < K; k0 += 64) {
#pragma unroll
    for (int i = 0; i < 4; i++) {
      int c = wid * 4 + i;
      int row = c * 8 + srow;
      __builtin_amdgcn_global_load_lds(
          (gbl_void*)&A[(size_t)(m0 + row) * K + k0 + scol],
          (lds_void*)(As + c * 512), 16, 0, 0);
      __builtin_amdgcn_global_load_lds(
          (gbl_void*)&Bt[(size_t)(n0 + row) * K + k0 + scol],
          (lds_void*)(Bs + c * 512), 16, 0, 0);
    }
    __syncthreads();
#pragma unroll
    for (int kk = 0; kk < 64; kk += 32) {
      short8 a[4], bb[4];
#pragma unroll
      for (int m = 0; m < 4; m++)
        a[m] = *(const short8*)&As[(wm + m * 16 + (lane & 15)) * 64 + kk +
                                   8 * (lane >> 4)];
#pragma unroll
      for (int n = 0; n < 4; n++)
        bb[n] = *(const short8*)&Bs[(wn + n * 16 + (lane & 15)) * 64 + kk +
                                    8 * (lane >> 4)];
#pragma unroll
      for (int m = 0; m < 4; m++)
#pragma unroll
        for (int n = 0; n < 4; n++)
          acc[m][n] = __builtin_amdgcn_mfma_f32_16x16x32_bf16(a[m], bb[n],
                                                              acc[m][n], 0, 0, 0);
    }
    __syncthreads();
  }

  int r0 = (lane >> 4) * 4;
  int cc = lane & 15;
#pragma unroll
  for (int m = 0; m < 4; m++) {
#pragma unroll
    for (int r = 0; r < 4; r++) {
      int row = m0 + wm + m * 16 + r0 + r;
      if (row >= total) continue;
      int pa = tpos[row];
      if (pa < 0) continue;
      int p = pa & (MAXT - 1);
#pragma unroll
      for (int n = 0; n < 4; n++) {
        int col = n0 + wn + n * 16 + cc;
        float v = acc[m][n][r] + bias[col] + pos_emb[p * H_ + col];
        out[(size_t)pa * H_ + col] = v;
      }
    }
  }
}

// ---------------------------------------------------------------------------
// merge2: sep rows (sep_token + pos_emb), zero-fill empty positions, mm.
// Token positions already written by gemm2_scatter.
// ---------------------------------------------------------------------------
__global__ void merge2_kernel(const int* __restrict__ gids,
                              const int* __restrict__ lengths,
                              const float* __restrict__ sep_token,
                              const float* __restrict__ pos_emb,
                              float* __restrict__ out) {
  int b = blockIdx.x, t = threadIdx.x;
  __shared__ signed char src[MAXT];  // 0 empty, 1 sep, 2 token
  __shared__ int g[L_];
  __shared__ int sh_total;
  int len = lengths[b];
  src[t] = 0;
  for (int l = t; l < len; l += 256) g[l] = gids[b * L_ + l];
  __syncthreads();
  if (t == 0) {
    int nsep = 0;
    for (int l = 0; l + 1 < len; l++)
      if (g[l] != g[l + 1]) nsep++;
    int total = len + nsep;
    sh_total = total;
    int off = MAXT - total;
    int sb = 0;
    for (int l = 0; l < len; l++) {
      int ti = off + l + sb;
      if (ti >= 0) src[ti] = 2;
      if (l + 1 < len && g[l] != g[l + 1]) {
        if (ti + 1 >= 0) src[ti + 1] = 1;
        sb++;
      }
    }
  }
  __syncthreads();
  int total = sh_total;
  int mlen = min(total, MAXT);

  int q = t >> 6, lane = t & 63, c4 = lane * 4;
  float4 sep4 = *(const float4*)&sep_token[c4];
  float* orow = out + (size_t)b * MAXT * H_;
  for (int p0 = 0; p0 < MAXT; p0 += 4) {
    int p = p0 + q;
    int s = src[p];
    if (s == 2) continue;  // token: written by gemm2_scatter
    float4 v;
    if (s == 1) {
      float4 pe = *(const float4*)&pos_emb[p * H_ + c4];
      v.x = sep4.x + pe.x; v.y = sep4.y + pe.y;
      v.z = sep4.z + pe.z; v.w = sep4.w + pe.w;
    } else {
      v.x = 0.f; v.y = 0.f; v.z = 0.f; v.w = 0.f;
    }
    *(float4*)&orow[(size_t)p * H_ + c4] = v;
  }
  float* mm = out + (size_t)B_ * MAXT * H_;
  mm[b * MAXT + t] = (t >= MAXT - mlen) ? 1.0f : 0.0f;
}

// ---------------------------------------------------------------------------
// launch
// ---------------------------------------------------------------------------
extern "C" void kernel_launch(void* const* d_in, const int* in_sizes, int n_in,
                              void* d_out, int out_size, void* d_ws,
                              size_t ws_size, hipStream_t stream) {
  const int* tok0 = (const int*)d_in[0];
  const int* tok1 = (const int*)d_in[1];
  const int* tok2 = (const int*)d_in[2];
  const int* tok3 = (const int*)d_in[3];
  const int* tgap = (const int*)d_in[4];
  const int* gid  = (const int*)d_in[5];
  const int* lengths = (const int*)d_in[6];
  const float* token_emb = (const float*)d_in[7];
  const float* gamma = (const float*)d_in[8];
  const float* beta  = (const float*)d_in[9];
  const float* w1 = (const float*)d_in[10];
  const float* b1 = (const float*)d_in[11];
  const float* w2 = (const float*)d_in[12];
  const float* b2 = (const float*)d_in[13];
  const float* tg_emb = (const float*)d_in[14];
  const float* g_emb  = (const float*)d_in[15];
  const float* pos_emb = (const float*)d_in[16];
  const float* sep_tok = (const float*)d_in[17];

  // workspace layout (bytes):
  //   x     bf16 [<=51200][1536] @ 0          (157,286,400)
  //   tpos  int  [<=51200]       @ 0          (aliases x; written after GEMM1)
  //   h     bf16 [<=51200][1024] @ 157286400  (104,857,600)
  //   w1t   bf16 [1024][1536]    @ 262144000  (  3,145,728)
  //   w2t   bf16 [256][1024]     @ 265289728  (    524,288)
  //   offsets int[257]           @ 265814016  (      1,028)
  const size_t NEEDED = 265815044;
  if (ws_size < NEEDED) return;

  char* ws = (char*)d_ws;
  __hip_bfloat16* x = (__hip_bfloat16*)ws;
  int* tpos = (int*)ws;  // aliases x (x dead after GEMM1)
  __hip_bfloat16* h = (__hip_bfloat16*)(ws + 157286400);
  __hip_bfloat16* w1t = (__hip_bfloat16*)(ws + 262144000);
  __hip_bfloat16* w2t = (__hip_bfloat16*)(ws + 265289728);
  int* offsets = (int*)(ws + 265814016);

  scan_offsets<<<1, 64, 0, stream>>>(lengths, offsets);
  zero_pad_x<<<256, 256, 0, stream>>>(x, offsets);

  transpose_to_bf16<<<dim3(1024 / 32, 1536 / 32), 256, 0, stream>>>(w1, w1t,
                                                                    1536, 1024);
  transpose_to_bf16<<<dim3(256 / 32, 1024 / 32), 256, 0, stream>>>(w2, w2t,
                                                                   1024, 256);

  embed_ln_kernel<<<dim3(L_, B_), 384, 0, stream>>>(
      tok0, tok1, tok2, tok3, tgap, gid, lengths, offsets, token_emb, tg_emb,
      g_emb, gamma, beta, x);

  hipFuncSetAttribute((const void*)gemm1_8ph,
                      hipFuncAttributeMaxDynamicSharedMemorySize, 131072);
  gemm1_8ph<<<256, 512, 131072, stream>>>(x, w1t, b1, h, offsets + B_);

  // x now dead -> tpos may overwrite its region
  tpos_kernel<<<B_, 64, 0, stream>>>(gid, lengths, offsets, tpos);

  gemm2_scatter<<<dim3(H_ / 128, NPOS / 128), 256, 0, stream>>>(
      h, w2t, b2, tpos, pos_emb, (float*)d_out, offsets + B_, H_, FOURH);

  merge2_kernel<<<B_, 256, 0, stream>>>(gid, lengths, sep_tok, pos_emb,
                                        (float*)d_out);
}

// Round 9
// 254.420 us; speedup vs baseline: 1.6536x; 1.0111x over previous
//
#include <hip/hip_runtime.h>
#include <hip/hip_bf16.h>
#include <math.h>

// Problem constants
#define B_    256
#define L_    200
#define H_    256
#define MAXT  256
#define SIXH  1536
#define FOURH 1024
#define NPOS  (B_ * L_)   // 51200

typedef __attribute__((ext_vector_type(8))) short short8;
typedef __attribute__((ext_vector_type(4))) float f32x4;

typedef __attribute__((address_space(3))) void lds_void;
typedef const __attribute__((address_space(1))) void gbl_void;

#define ASM_BAR() asm volatile("s_barrier" ::: "memory")
#define VMCNT4()  asm volatile("s_waitcnt vmcnt(4)" ::: "memory")
#define VMCNT0()  asm volatile("s_waitcnt vmcnt(0)" ::: "memory")

// ---------------------------------------------------------------------------
// Exclusive prefix-sum of lengths -> offsets[0..B_], offsets[B_] = total valid
// ---------------------------------------------------------------------------
__global__ void scan_offsets(const int* __restrict__ lengths,
                             int* __restrict__ offsets) {
  if (threadIdx.x == 0) {
    int acc = 0;
    for (int b = 0; b < B_; b++) { offsets[b] = acc; acc += lengths[b]; }
    offsets[B_] = acc;
  }
}

// ---------------------------------------------------------------------------
// Zero the pad rows of x: rows [total, roundup256(total))
// ---------------------------------------------------------------------------
__global__ void zero_pad_x(__hip_bfloat16* __restrict__ x,
                           const int* __restrict__ offsets) {
  int total = offsets[B_];
  int padded = (total + 255) & ~255;
  int row = total + blockIdx.x;
  if (row >= padded) return;
  int t = threadIdx.x;
#pragma unroll
  for (int j = 0; j < 6; j++)
    x[(size_t)row * SIXH + j * 256 + t] = __float2bfloat16(0.0f);
}

// ---------------------------------------------------------------------------
// Per compacted row: absolute output slot b*MAXT+p (or -1).
// ---------------------------------------------------------------------------
__global__ void tpos_kernel(const int* __restrict__ gids,
                            const int* __restrict__ lengths,
                            const int* __restrict__ offsets,
                            int* __restrict__ tpos) {
  int b = blockIdx.x, t = threadIdx.x;
  __shared__ int g[L_];
  int len = lengths[b];
  for (int l = t; l < len; l += 64) g[l] = gids[b * L_ + l];
  __syncthreads();
  if (t != 0) return;
  int base = offsets[b];
  int nsep = 0;
  for (int l = 0; l + 1 < len; l++)
    if (g[l] != g[l + 1]) nsep++;
  int total = len + nsep;
  int off = MAXT - total;
  int sb = 0;
  for (int l = 0; l < len; l++) {
    int ti = off + l + sb;
    tpos[base + l] = (ti >= 0) ? (b * MAXT + ti) : -1;
    if (l + 1 < len && g[l] != g[l + 1]) sb++;
  }
}

// ---------------------------------------------------------------------------
// Transpose + f32->bf16 convert: in [R][C] f32 -> out [C][R] bf16
// ---------------------------------------------------------------------------
__global__ void transpose_to_bf16(const float* __restrict__ in,
                                  __hip_bfloat16* __restrict__ out,
                                  int R, int C) {
  __shared__ float tile[32][33];
  int tc = blockIdx.x, tr = blockIdx.y;
  int tx = threadIdx.x & 31, ty = threadIdx.x >> 5;  // 32 x 8
#pragma unroll
  for (int i = 0; i < 4; i++) {
    int r = tr * 32 + ty + i * 8;
    int c = tc * 32 + tx;
    tile[ty + i * 8][tx] = in[(size_t)r * C + c];
  }
  __syncthreads();
#pragma unroll
  for (int i = 0; i < 4; i++) {
    int orow = tc * 32 + ty + i * 8;  // out row = original col
    int ocol = tr * 32 + tx;          // out col = original row
    out[(size_t)orow * R + ocol] = __float2bfloat16(tile[tx][ty + i * 8]);
  }
}

// ---------------------------------------------------------------------------
// Fused embedding gather + concat + LayerNorm -> x bf16 [row][1536]
// 384 threads = 6 waves; wave j handles table j; thread = float4 (4 channels).
// ---------------------------------------------------------------------------
__global__ void embed_ln_kernel(const int* __restrict__ tok0,
                                const int* __restrict__ tok1,
                                const int* __restrict__ tok2,
                                const int* __restrict__ tok3,
                                const int* __restrict__ tgap,
                                const int* __restrict__ gid,
                                const int* __restrict__ lengths,
                                const int* __restrict__ offsets,
                                const float* __restrict__ token_emb,
                                const float* __restrict__ tg_emb,
                                const float* __restrict__ g_emb,
                                const float* __restrict__ gamma,
                                const float* __restrict__ beta,
                                __hip_bfloat16* __restrict__ xout) {
  int l = blockIdx.x, b = blockIdx.y;
  if (l >= lengths[b]) return;  // compaction: skip invalid positions
  int pos = b * L_ + l;
  int row = offsets[b] + l;
  int t = threadIdx.x;
  int wv = t >> 6;          // table index 0..5
  int ln = t & 63;
  int c4 = ln * 4;          // channel within table

  const float* tab;
  int idx;
  if (wv == 0)      { tab = token_emb; idx = tok0[pos]; }
  else if (wv == 1) { tab = token_emb; idx = tok1[pos]; }
  else if (wv == 2) { tab = token_emb; idx = tok2[pos]; }
  else if (wv == 3) { tab = token_emb; idx = tok3[pos]; }
  else if (wv == 4) { tab = tg_emb;    idx = min(max(tgap[pos], 0), 64); }
  else              { tab = g_emb;     idx = gid[pos]; }

  float4 v = *(const float4*)&tab[(size_t)idx * H_ + c4];

  float s = v.x + v.y + v.z + v.w;
  float q = v.x * v.x + v.y * v.y + v.z * v.z + v.w * v.w;
#pragma unroll
  for (int o = 32; o; o >>= 1) { s += __shfl_down(s, o); q += __shfl_down(q, o); }
  __shared__ float ps[6], pq[6];
  if (ln == 0) { ps[wv] = s; pq[wv] = q; }
  __syncthreads();
  float ts = 0.f, tq = 0.f;
#pragma unroll
  for (int k = 0; k < 6; k++) { ts += ps[k]; tq += pq[k]; }
  float mu = ts * (1.0f / 1536.0f);
  float var = tq * (1.0f / 1536.0f) - mu * mu;
  float rstd = rsqrtf(var + 1e-5f);

  int cbase = wv * 256 + c4;
  float4 gm = *(const float4*)&gamma[cbase];
  float4 bt = *(const float4*)&beta[cbase];
  float y0 = (v.x - mu) * rstd * gm.x + bt.x;
  float y1 = (v.y - mu) * rstd * gm.y + bt.y;
  float y2 = (v.z - mu) * rstd * gm.z + bt.z;
  float y3 = (v.w - mu) * rstd * gm.w + bt.w;
  __hip_bfloat16 h0 = __float2bfloat16(y0), h1 = __float2bfloat16(y1);
  __hip_bfloat16 h2 = __float2bfloat16(y2), h3 = __float2bfloat16(y3);
  ushort4 pk;
  pk.x = *(unsigned short*)&h0; pk.y = *(unsigned short*)&h1;
  pk.z = *(unsigned short*)&h2; pk.w = *(unsigned short*)&h3;
  *(ushort4*)&xout[(size_t)row * SIXH + cbase] = pk;
}

// ---------------------------------------------------------------------------
// GEMM1 (persistent, XCD-sibling-grouped, 2-barrier K-loop): 256x256 tile,
// BK=64, 8 waves, XOR-swizzled LDS (0 conflicts, R4), stage pattern and
// vmcnt(4) counting IDENTICAL to the R4-verified schedule. R9 change: only
// 2 barriers per K-tile (bar_mid, bar_end) instead of 8 — every STAGE
// target's readers complete before the immediately preceding barrier
// (audited), so waves drift within half-K-tile windows and one wave's
// ds_reads overlap another's MFMA (R8 model: 512cy LDS + 620cy MFMA were
// barrier-serialized -> 55% ceiling; this removes the serialization).
// ---------------------------------------------------------------------------
__global__ __launch_bounds__(512, 2)
void gemm1_8ph(const __hip_bfloat16* __restrict__ A,
               const __hip_bfloat16* __restrict__ Bt,
               const float* __restrict__ bias,
               __hip_bfloat16* __restrict__ out,
               const int* __restrict__ total_ptr) {
  constexpr int K = SIXH;     // 1536
  constexpr int NT = K / 64;  // 24 K-tiles
  constexpr int N = FOURH;    // 1024

  extern __shared__ __align__(16) char lds[];

  int total = total_ptr[0];
  int padded = (total + 255) & ~255;
  int num_mt = padded >> 8;

  int bid = blockIdx.x;        // 0..255
  int xcd = bid & 7;
  int slot = bid >> 3;         // 0..31
  int nt = slot & 3;           // 0..3
  int mtb = slot >> 2;         // 0..7
  int n0 = nt * 256;

  int tid = threadIdx.x;
  int lane = tid & 63;
  int w = tid >> 6;
  int wave_m = w >> 2;
  int wave_n = w & 3;

  int r15 = lane & 15, g = lane >> 4;
  int slot_r = (((r15 & 1) << 2) | g) ^ (r15 >> 1);
  int lane_off = (r15 >> 1) * 128 + slot_r * 16;

  int s0 = (tid & 7) ^ ((tid >> 3) & 7);
  int scol = (s0 & 3) * 8;
  int row0 = ((tid >> 3) << 1) + (s0 >> 2);
  int ldst0 = w * 1024;

  // bias hoist: 4 cols per thread, fixed for the whole block
  float bv4[4];
#pragma unroll
  for (int ni = 0; ni < 4; ni++)
    bv4[ni] = bias[n0 + wave_n * 64 + ni * 16 + r15];

#define REGA(d, h) (lds + (d) * 65536 + (h) * 16384)
#define REGB(d, h) (lds + (d) * 65536 + 32768 + (h) * 16384)

#define STAGE(P, t0, kt, h, rb)                                                \
  do {                                                                         \
    __builtin_amdgcn_global_load_lds(                                          \
        (gbl_void*)((P) + (size_t)((t0) + row0) * K + (kt) * 64 + (h) * 32 +   \
                    scol),                                                     \
        (lds_void*)((rb) + ldst0), 16, 0, 0);                                  \
    __builtin_amdgcn_global_load_lds(                                          \
        (gbl_void*)((P) + (size_t)((t0) + row0 + 128) * K + (kt) * 64 +        \
                    (h) * 32 + scol),                                          \
        (lds_void*)((rb) + 8192 + ldst0), 16, 0, 0);                           \
  } while (0)

  for (int mt = xcd + 8 * mtb; mt < num_mt; mt += 64) {
    int m0 = mt * 256;

    f32x4 acc[8][4] = {};

    // prologue: kt0 fully + kt1 khalf0 (12 loads; vmcnt(4) => kt0 resident)
    STAGE(A, m0, 0, 0, REGA(0, 0));
    STAGE(Bt, n0, 0, 0, REGB(0, 0));
    STAGE(A, m0, 0, 1, REGA(0, 1));
    STAGE(Bt, n0, 0, 1, REGB(0, 1));
    STAGE(A, m0, 1, 0, REGA(1, 0));
    STAGE(Bt, n0, 1, 0, REGB(1, 0));
    VMCNT4();
    ASM_BAR();

    for (int kt = 0; kt < NT; ++kt) {
      int d = kt & 1;
      int kc1 = (kt + 1 < NT) ? kt + 1 : NT - 1;
      int kc2 = (kt + 2 < NT) ? kt + 2 : NT - 1;
      char* A0 = REGA(d, 0); char* A1 = REGA(d, 1);
      char* B0 = REGB(d, 0); char* B1 = REGB(d, 1);
      char* An1 = REGA(d ^ 1, 1);
      char* Bn1 = REGB(d ^ 1, 1);

      short8 a[4], b[4];

      // ======== first half: kh0 (reads A0/B0; stages next-dbuf kh1) ========
      // stage targets An1/Bn1: last read in kt-1's second half, before the
      // bar_end we just crossed -> safe.
#pragma unroll
      for (int ni = 0; ni < 4; ni++)
        b[ni] = *(const short8*)(B0 + (wave_n * 64 + ni * 16) * 64 + lane_off);
#pragma unroll
      for (int j = 0; j < 4; j++)
        a[j] = *(const short8*)(A0 + (wave_m * 128 + j * 16) * 64 + lane_off);
      STAGE(A, m0, kc1, 1, An1);
      __builtin_amdgcn_s_setprio(1);
#pragma unroll
      for (int j = 0; j < 4; j++)
#pragma unroll
        for (int ni = 0; ni < 4; ni++)
          acc[j][ni] = __builtin_amdgcn_mfma_f32_16x16x32_bf16(a[j], b[ni],
                                                               acc[j][ni], 0, 0, 0);
      __builtin_amdgcn_s_setprio(0);
#pragma unroll
      for (int j = 0; j < 4; j++)
        a[j] = *(const short8*)(A0 + (wave_m * 128 + (4 + j) * 16) * 64 + lane_off);
      STAGE(Bt, n0, kc1, 1, Bn1);
      __builtin_amdgcn_s_setprio(1);
#pragma unroll
      for (int j = 0; j < 4; j++)
#pragma unroll
        for (int ni = 0; ni < 4; ni++)
          acc[4 + j][ni] = __builtin_amdgcn_mfma_f32_16x16x32_bf16(
              a[j], b[ni], acc[4 + j][ni], 0, 0, 0);
      __builtin_amdgcn_s_setprio(0);
      ASM_BAR();  // bar_mid: kh0 reads (all waves) done -> kh0 may be staged

      // ======== second half: kh1 (reads A1/B1; stages this-dbuf kh0) =======
      // A1/B1 staged during kt-1 first half, retired by kt-1's vmcnt(4),
      // cross-wave visible via kt-1's bar_end.
#pragma unroll
      for (int ni = 0; ni < 4; ni++)
        b[ni] = *(const short8*)(B1 + (wave_n * 64 + ni * 16) * 64 + lane_off);
#pragma unroll
      for (int j = 0; j < 4; j++)
        a[j] = *(const short8*)(A1 + (wave_m * 128 + j * 16) * 64 + lane_off);
      STAGE(A, m0, kc2, 0, A0);
      __builtin_amdgcn_s_setprio(1);
#pragma unroll
      for (int j = 0; j < 4; j++)
#pragma unroll
        for (int ni = 0; ni < 4; ni++)
          acc[j][ni] = __builtin_amdgcn_mfma_f32_16x16x32_bf16(a[j], b[ni],
                                                               acc[j][ni], 0, 0, 0);
      __builtin_amdgcn_s_setprio(0);
#pragma unroll
      for (int j = 0; j < 4; j++)
        a[j] = *(const short8*)(A1 + (wave_m * 128 + (4 + j) * 16) * 64 + lane_off);
      STAGE(Bt, n0, kc2, 0, B0);
      __builtin_amdgcn_s_setprio(1);
#pragma unroll
      for (int j = 0; j < 4; j++)
#pragma unroll
        for (int ni = 0; ni < 4; ni++)
          acc[4 + j][ni] = __builtin_amdgcn_mfma_f32_16x16x32_bf16(
              a[j], b[ni], acc[4 + j][ni], 0, 0, 0);
      __builtin_amdgcn_s_setprio(0);
      VMCNT4();   // retires kt's kh1-stages + older; keeps newest 4 in flight
      ASM_BAR();  // bar_end
    }
    // drain stale clamped stage-loads before LDS regions are re-staged.
    VMCNT0();

    // epilogue: D mapping col = lane&15, row = 4*(lane>>4)+reg
    int r0 = g * 4;
#pragma unroll
    for (int mi = 0; mi < 8; mi++)
#pragma unroll
      for (int ni = 0; ni < 4; ni++) {
        int col = n0 + wave_n * 64 + ni * 16 + r15;
        float bv = bv4[ni];
#pragma unroll
        for (int r = 0; r < 4; r++) {
          int row = m0 + wave_m * 128 + mi * 16 + r0 + r;
          float v = acc[mi][ni][r] + bv;
          v = v / (1.0f + __expf(-v));  // silu
          out[(size_t)row * N + col] = __float2bfloat16(v);
        }
      }
  }
#undef STAGE
#undef REGA
#undef REGB
}

// ---------------------------------------------------------------------------
// GEMM2 with fused scatter epilogue (proven 128x128 form; R7's 128x256
// reshape spilled acc -> reverted). C = h*w2t^T + b2, written to d_out at
// tpos[row] with pos_emb added.
// ---------------------------------------------------------------------------
__global__ void gemm2_scatter(const __hip_bfloat16* __restrict__ A,
                              const __hip_bfloat16* __restrict__ Bt,
                              const float* __restrict__ bias,
                              const int* __restrict__ tpos,
                              const float* __restrict__ pos_emb,
                              float* __restrict__ out,
                              const int* __restrict__ total_ptr,
                              int N, int K) {
  int m0 = blockIdx.y * 128;
  int total = total_ptr[0];
  int padded = (total + 127) & ~127;
  if (m0 >= padded) return;

  __shared__ __hip_bfloat16 As[128 * 64];
  __shared__ __hip_bfloat16 Bs[128 * 64];
  int n0 = blockIdx.x * 128;
  int tid = threadIdx.x;
  int lane = tid & 63, wid = tid >> 6;
  int wm = (wid >> 1) * 64, wn = (wid & 1) * 64;

  int srow = (lane >> 3);
  int scol = (lane & 7) * 8;

  f32x4 acc[4][4] = {};

  for (int k0 = 0; k0 < K; k0 += 64) {
#pragma unroll
    for (int i = 0; i < 4; i++) {
      int c = wid * 4 + i;
      int row = c * 8 + srow;
      __builtin_amdgcn_global_load_lds(
          (gbl_void*)&A[(size_t)(m0 + row) * K + k0 + scol],
          (lds_void*)(As + c * 512), 16, 0, 0);
      __builtin_amdgcn_global_load_lds(
          (gbl_void*)&Bt[(size_t)(n0 + row) * K + k0 + scol],
          (lds_void*)(Bs + c * 512), 16, 0, 0);
    }
    __syncthreads();
#pragma unroll
    for (int kk = 0; kk < 64; kk += 32) {
      short8 a[4], bb[4];
#pragma unroll
      for (int m = 0; m < 4; m++)
        a[m] = *(const short8*)&As[(wm + m * 16 + (lane & 15)) * 64 + kk +
                                   8 * (lane >> 4)];
#pragma unroll
      for (int n = 0; n < 4; n++)
        bb[n] = *(const short8*)&Bs[(wn + n * 16 + (lane & 15)) * 64 + kk +
                                    8 * (lane >> 4)];
#pragma unroll
      for (int m = 0; m < 4; m++)
#pragma unroll
        for (int n = 0; n < 4; n++)
          acc[m][n] = __builtin_amdgcn_mfma_f32_16x16x32_bf16(a[m], bb[n],
                                                              acc[m][n], 0, 0, 0);
    }
    __syncthreads();
  }

  int r0 = (lane >> 4) * 4;
  int cc = lane & 15;
#pragma unroll
  for (int m = 0; m < 4; m++) {
#pragma unroll
    for (int r = 0; r < 4; r++) {
      int row = m0 + wm + m * 16 + r0 + r;
      if (row >= total) continue;
      int pa = tpos[row];
      if (pa < 0) continue;
      int p = pa & (MAXT - 1);
#pragma unroll
      for (int n = 0; n < 4; n++) {
        int col = n0 + wn + n * 16 + cc;
        float v = acc[m][n][r] + bias[col] + pos_emb[p * H_ + col];
        out[(size_t)pa * H_ + col] = v;
      }
    }
  }
}

// ---------------------------------------------------------------------------
// merge2: sep rows (sep_token + pos_emb), zero-fill empty positions, mm.
// Token positions already written by gemm2_scatter.
// ---------------------------------------------------------------------------
__global__ void merge2_kernel(const int* __restrict__ gids,
                              const int* __restrict__ lengths,
                              const float* __restrict__ sep_token,
                              const float* __restrict__ pos_emb,
                              float* __restrict__ out) {
  int b = blockIdx.x, t = threadIdx.x;
  __shared__ signed char src[MAXT];  // 0 empty, 1 sep, 2 token
  __shared__ int g[L_];
  __shared__ int sh_total;
  int len = lengths[b];
  src[t] = 0;
  for (int l = t; l < len; l += 256) g[l] = gids[b * L_ + l];
  __syncthreads();
  if (t == 0) {
    int nsep = 0;
    for (int l = 0; l + 1 < len; l++)
      if (g[l] != g[l + 1]) nsep++;
    int total = len + nsep;
    sh_total = total;
    int off = MAXT - total;
    int sb = 0;
    for (int l = 0; l < len; l++) {
      int ti = off + l + sb;
      if (ti >= 0) src[ti] = 2;
      if (l + 1 < len && g[l] != g[l + 1]) {
        if (ti + 1 >= 0) src[ti + 1] = 1;
        sb++;
      }
    }
  }
  __syncthreads();
  int total = sh_total;
  int mlen = min(total, MAXT);

  int q = t >> 6, lane = t & 63, c4 = lane * 4;
  float4 sep4 = *(const float4*)&sep_token[c4];
  float* orow = out + (size_t)b * MAXT * H_;
  for (int p0 = 0; p0 < MAXT; p0 += 4) {
    int p = p0 + q;
    int s = src[p];
    if (s == 2) continue;  // token: written by gemm2_scatter
    float4 v;
    if (s == 1) {
      float4 pe = *(const float4*)&pos_emb[p * H_ + c4];
      v.x = sep4.x + pe.x; v.y = sep4.y + pe.y;
      v.z = sep4.z + pe.z; v.w = sep4.w + pe.w;
    } else {
      v.x = 0.f; v.y = 0.f; v.z = 0.f; v.w = 0.f;
    }
    *(float4*)&orow[(size_t)p * H_ + c4] = v;
  }
  float* mm = out + (size_t)B_ * MAXT * H_;
  mm[b * MAXT + t] = (t >= MAXT - mlen) ? 1.0f : 0.0f;
}

// ---------------------------------------------------------------------------
// launch
// ---------------------------------------------------------------------------
extern "C" void kernel_launch(void* const* d_in, const int* in_sizes, int n_in,
                              void* d_out, int out_size, void* d_ws,
                              size_t ws_size, hipStream_t stream) {
  const int* tok0 = (const int*)d_in[0];
  const int* tok1 = (const int*)d_in[1];
  const int* tok2 = (const int*)d_in[2];
  const int* tok3 = (const int*)d_in[3];
  const int* tgap = (const int*)d_in[4];
  const int* gid  = (const int*)d_in[5];
  const int* lengths = (const int*)d_in[6];
  const float* token_emb = (const float*)d_in[7];
  const float* gamma = (const float*)d_in[8];
  const float* beta  = (const float*)d_in[9];
  const float* w1 = (const float*)d_in[10];
  const float* b1 = (const float*)d_in[11];
  const float* w2 = (const float*)d_in[12];
  const float* b2 = (const float*)d_in[13];
  const float* tg_emb = (const float*)d_in[14];
  const float* g_emb  = (const float*)d_in[15];
  const float* pos_emb = (const float*)d_in[16];
  const float* sep_tok = (const float*)d_in[17];

  // workspace layout (bytes):
  //   x     bf16 [<=51200][1536] @ 0          (157,286,400)
  //   tpos  int  [<=51200]       @ 0          (aliases x; written after GEMM1)
  //   h     bf16 [<=51200][1024] @ 157286400  (104,857,600)
  //   w1t   bf16 [1024][1536]    @ 262144000  (  3,145,728)
  //   w2t   bf16 [256][1024]     @ 265289728  (    524,288)
  //   offsets int[257]           @ 265814016  (      1,028)
  const size_t NEEDED = 265815044;
  if (ws_size < NEEDED) return;

  char* ws = (char*)d_ws;
  __hip_bfloat16* x = (__hip_bfloat16*)ws;
  int* tpos = (int*)ws;  // aliases x (x dead after GEMM1)
  __hip_bfloat16* h = (__hip_bfloat16*)(ws + 157286400);
  __hip_bfloat16* w1t = (__hip_bfloat16*)(ws + 262144000);
  __hip_bfloat16* w2t = (__hip_bfloat16*)(ws + 265289728);
  int* offsets = (int*)(ws + 265814016);

  scan_offsets<<<1, 64, 0, stream>>>(lengths, offsets);
  zero_pad_x<<<256, 256, 0, stream>>>(x, offsets);

  transpose_to_bf16<<<dim3(1024 / 32, 1536 / 32), 256, 0, stream>>>(w1, w1t,
                                                                    1536, 1024);
  transpose_to_bf16<<<dim3(256 / 32, 1024 / 32), 256, 0, stream>>>(w2, w2t,
                                                                   1024, 256);

  embed_ln_kernel<<<dim3(L_, B_), 384, 0, stream>>>(
      tok0, tok1, tok2, tok3, tgap, gid, lengths, offsets, token_emb, tg_emb,
      g_emb, gamma, beta, x);

  hipFuncSetAttribute((const void*)gemm1_8ph,
                      hipFuncAttributeMaxDynamicSharedMemorySize, 131072);
  gemm1_8ph<<<256, 512, 131072, stream>>>(x, w1t, b1, h, offsets + B_);

  // x now dead -> tpos may overwrite its region
  tpos_kernel<<<B_, 64, 0, stream>>>(gid, lengths, offsets, tpos);

  gemm2_scatter<<<dim3(H_ / 128, NPOS / 128), 256, 0, stream>>>(
      h, w2t, b2, tpos, pos_emb, (float*)d_out, offsets + B_, H_, FOURH);

  merge2_kernel<<<B_, 256, 0, stream>>>(gid, lengths, sep_tok, pos_emb,
                                        (float*)d_out);
}